// Round 2
// baseline (439.670 us; speedup 1.0000x reference)
//
#include <hip/hip_runtime.h>

// SelectiveAttnMLA on MI355X (gfx950).
// B=4 S=2048 Hq=16 G=4 D=192 DV=128 BLK=64 NB=32 TOPK=16, out fp32 (8192x2048).
//
// R5: software-pipelined KV loop (T3/T4/T14 from the technique catalog):
//     - V fragments per-lane in REGISTERS (16x half8 = 64 VGPR), plain loads
//       issued one block ahead; compiler sinks the wait to PV -> latency hides
//       under QK^T+softmax.
//     - K double-buffered in LDS (2x24KB) via global_load_lds for the NEXT
//       selected block, with counted s_waitcnt vmcnt(16) + raw s_barrier at
//       iteration bottom: the 16 in-flight V loads cross the barrier, only the
//       6 K stages must land. ONE barrier/iter, no vmcnt(0) drain in loop.
//     - uniform control flow: every wave computes every block-selected kb
//       (per-lane msel zeroing is exact; inflated row-max is shift-invariant).

typedef __attribute__((ext_vector_type(8))) _Float16 half8;
typedef __attribute__((ext_vector_type(4))) float f32x4;
typedef __attribute__((ext_vector_type(4))) unsigned int u32x4;

__device__ __forceinline__ half8 cvt8(const float4* p) {
  float4 a = p[0], b = p[1];
  half8 r;
  r[0] = (_Float16)a.x; r[1] = (_Float16)a.y; r[2] = (_Float16)a.z; r[3] = (_Float16)a.w;
  r[4] = (_Float16)b.x; r[5] = (_Float16)b.y; r[6] = (_Float16)b.z; r[7] = (_Float16)b.w;
  return r;
}

__device__ __forceinline__ half8 cvt8s(const float4* p, float s) {
  float4 a = p[0], b = p[1];
  half8 r;
  r[0] = (_Float16)(a.x * s); r[1] = (_Float16)(a.y * s);
  r[2] = (_Float16)(a.z * s); r[3] = (_Float16)(a.w * s);
  r[4] = (_Float16)(b.x * s); r[5] = (_Float16)(b.y * s);
  r[6] = (_Float16)(b.z * s); r[7] = (_Float16)(b.w * s);
  return r;
}

__device__ __forceinline__ void async16(const void* g, void* l) {
  __builtin_amdgcn_global_load_lds(
      (const __attribute__((address_space(1))) void*)g,
      (__attribute__((address_space(3))) void*)l, 16, 0, 0);
}

__device__ __forceinline__ f32x4 vmax4(f32x4 a, f32x4 b) {
  f32x4 r;
  r[0] = fmaxf(a[0], b[0]); r[1] = fmaxf(a[1], b[1]);
  r[2] = fmaxf(a[2], b[2]); r[3] = fmaxf(a[3], b[3]);
  return r;
}

// ---------------- fused K/V fragment prepass (unchanged from R4) ----------------
__global__ __launch_bounds__(256) void kv_prep(const float* __restrict__ k,
                                               const float* __restrict__ v,
                                               _Float16* __restrict__ kf,
                                               _Float16* __restrict__ vf) {
  __shared__ float lb[64 * 196];      // K phase: [64][196]; V phase: [64][132]
  int blk = blockIdx.x;               // (b*16+h)*32 + kb
  int bh = blk >> 5, kb = blk & 31;
  int b = bh >> 4, h = bh & 15;
  int tid = threadIdx.x;

  // ---- K: load 64 rows x 192 f32, coalesced ----
  const float* ksrc = k + ((long)(b * 2048 + kb * 64) * 16 + h) * 192;
#pragma unroll
  for (int it = 0; it < 12; ++it) {
    int idx = it * 256 + tid;         // 3072 float4
    int kk = idx / 48, c4 = idx - kk * 48;
    *(float4*)(&lb[kk * 196 + c4 * 4]) = *(const float4*)(ksrc + (long)kk * 3072 + c4 * 4);
  }
  __syncthreads();
  _Float16* kdst = kf + (long)blk * 12288;
#pragma unroll
  for (int it = 0; it < 6; ++it) {
    int oct = it * 256 + tid;         // 1536 octets
    int frag = oct >> 6, lane = oct & 63;
    int ntile = frag / 6, kc = frag - ntile * 6;
    int lm = lane & 15;
    // permuted row: stored slot (ntile, lm) <- actual key (lm>>2)*16 + ntile*4 + (lm&3)
    int n = ((lm >> 2) << 4) + ntile * 4 + (lm & 3);
    int d = kc * 32 + ((lane >> 4) << 3);
    *(half8*)(kdst + (long)oct * 8) = cvt8((const float4*)(&lb[n * 196 + d]));
  }
  __syncthreads();

  // ---- V: load 64 rows x 128 f32, coalesced; emit transposed frags ----
  const float* vsrc = v + ((long)(b * 2048 + kb * 64) * 16 + h) * 128;
#pragma unroll
  for (int it = 0; it < 8; ++it) {
    int idx = it * 256 + tid;         // 2048 float4
    int kk = idx >> 5, c4 = idx & 31;
    *(float4*)(&lb[kk * 132 + c4 * 4]) = *(const float4*)(vsrc + (long)kk * 2048 + c4 * 4);
  }
  __syncthreads();
  _Float16* vdst = vf + (long)blk * 8192;
#pragma unroll
  for (int it = 0; it < 4; ++it) {
    int oct = it * 256 + tid;         // 1024 octets
    int frag = oct >> 6, lane = oct & 63;
    int n0 = frag >> 1, kc = frag & 1;
    int dv = n0 * 16 + (lane & 15);
    int kbase = kc * 32 + ((lane >> 4) << 3);
    half8 o;
#pragma unroll
    for (int j = 0; j < 8; ++j) o[j] = (_Float16)lb[(kbase + j) * 132 + dv];
    *(half8*)(vdst + (long)oct * 8) = o;
  }
}

// ---------------- main attention (swapped operands, pipelined) ----------------
__global__ __launch_bounds__(256) void attn_main(const float* __restrict__ q,
                                                 const int* __restrict__ idx,
                                                 const _Float16* __restrict__ kf,
                                                 const _Float16* __restrict__ vf,
                                                 float* __restrict__ out) {
  constexpr float SCL = 0.07216878364870322f * 1.4426950408889634f;  // sm_scale*log2e
  int id = (int)blockIdx.x;
  int qb = 31 - (id >> 6);            // qb swizzle: CU gets mixed qb, fixed (b,h)
  int h = id & 15, b = (id >> 4) & 3, g = h >> 2;
  int tid = threadIdx.x;
  int w = tid >> 6, L = tid & 63;
  int Lm = L & 15, Lq = L >> 4;
  int m0 = w * 16;
  int t0 = b * 2048 + qb * 64;

  __shared__ __align__(16) char sh_k[2][24576];        // K frag double buffer
  __shared__ __align__(16) _Float16 Pbuf[4][16 * 72];  // per-wave [q][key], stride 144B
  __shared__ unsigned un_sh[4];

  const char* kfb = (const char*)(kf + (long)((b * 16 + h) * 32) * 12288);
  const _Float16* vfb = vf + (long)((b * 16 + h) * 32) * 8192;
  _Float16* pw = &Pbuf[w][0];

  auto stageK = [&](int kb, char* dst) {
    const char* kg = kfb + (long)kb * 24576;
#pragma unroll
    for (int c = 0; c < 6; ++c) {
      int ch = w + c * 4;
      async16(kg + ch * 1024 + L * 16, dst + ch * 1024);
    }
  };

  // V fragments in registers, loaded one block ahead.
  half8 vr[16];
  auto loadV = [&](int kb) {
    const half8* vg = (const half8*)(vfb + (long)kb * 8192);
#pragma unroll
    for (int j = 0; j < 16; ++j) vr[j] = vg[j * 64 + L];
  };

  // Q as B-operand: col = Lm (query row), k-slots = d
  half8 qa[6];
  const float* qrow = q + ((long)(t0 + m0 + Lm) * 16 + h) * 192;
#pragma unroll
  for (int c = 0; c < 6; ++c) qa[c] = cvt8s((const float4*)(qrow + c * 32 + Lq * 8), SCL);

  // prologue staging: block 0 is always selected (guaranteed by problem).
  stageK(0, sh_k[0]);
  loadV(0);

  // per-lane selection mask for THIS lane's query row (m0+Lm); int4 + lane-OR
  unsigned mrow;
  {
    const int4* ip = (const int4*)(idx + ((long)(t0 + m0 + Lm) * 4 + g) * 16);
    int4 iv = ip[Lq];
    unsigned mr = (1u << iv.x) | (1u << iv.y) | (1u << iv.z) | (1u << iv.w);
    mr |= __shfl_xor(mr, 16);
    mr |= __shfl_xor(mr, 32);
    mrow = mr;                        // full 16-pick mask of row m0+Lm
  }
  unsigned un = mrow;
  un |= __shfl_xor(un, 1);
  un |= __shfl_xor(un, 2);
  un |= __shfl_xor(un, 4);
  un |= __shfl_xor(un, 8);            // union over the wave's 16 rows
  if (L == 0) un_sh[w] = un;
  __syncthreads();                    // full drain (prologue only): K(0) staged, bm visible
  unsigned bm = un_sh[0] | un_sh[1] | un_sh[2] | un_sh[3];
  unsigned bmask = bm & ((2u << qb) - 1);   // bits 0..qb (qb=31: wraps to all-ones)

  f32x4 Oacc[8];                      // O^T tiles: row = dv (Lq*4+i), col = q (Lm)
#pragma unroll
  for (int n0 = 0; n0 < 8; ++n0) Oacc[n0] = (f32x4){0.f, 0.f, 0.f, 0.f};
  float m_i = -1e30f, l_i = 0.f;

  unsigned rem = bmask;               // bit 0 always set
  int kb = 0;
  int cur = 0;

  for (;;) {
    rem &= rem - 1;
    int nxt = rem ? (int)__builtin_ctz(rem) : -1;
    if (nxt >= 0) stageK(nxt, sh_k[cur ^ 1]);   // 6 async16, in flight through compute

    const half8* lkf = (const half8*)sh_k[cur];

    // S^T = K Q^T: lane holds scores of query Lm for actual keys Lq*16 + nt*4 + i
    f32x4 S[4];
#pragma unroll
    for (int nt = 0; nt < 4; ++nt) {
      f32x4 acc = {0.f, 0.f, 0.f, 0.f};
#pragma unroll
      for (int c = 0; c < 6; ++c)
        acc = __builtin_amdgcn_mfma_f32_16x16x32_f16(lkf[(nt * 6 + c) * 64 + L], qa[c], acc, 0, 0, 0);
      S[nt] = acc;
    }

    float p[4][4];
    float msel = ((mrow >> kb) & 1u) ? 1.0f : 0.0f;
    if (kb != qb) {
      // selection via per-row 0/1 multiply; inflated row-max from unselected
      // rows is exact (softmax shift-invariance), p*0 kills the values.
      f32x4 t = vmax4(vmax4(S[0], S[1]), vmax4(S[2], S[3]));
      float rmax = fmaxf(fmaxf(t[0], t[1]), fmaxf(t[2], t[3]));
      rmax = fmaxf(rmax, __shfl_xor(rmax, 16));
      rmax = fmaxf(rmax, __shfl_xor(rmax, 32));
      if (__any(rmax > m_i)) {
        float mn = fmaxf(m_i, rmax);
        float av = __builtin_amdgcn_exp2f(m_i - mn);
        m_i = mn;
        l_i *= av;
#pragma unroll
        for (int n0 = 0; n0 < 8; ++n0) Oacc[n0] *= av;
      }
      float ps[4];
#pragma unroll
      for (int nt = 0; nt < 4; ++nt) {
        float s0 = 0.f, s1 = 0.f;
#pragma unroll
        for (int i = 0; i < 4; i += 2) {
          float a = __builtin_amdgcn_exp2f(S[nt][i] - m_i) * msel;
          float c = __builtin_amdgcn_exp2f(S[nt][i + 1] - m_i) * msel;
          p[nt][i] = a; p[nt][i + 1] = c;
          s0 += a; s1 += c;
        }
        ps[nt] = s0 + s1;
      }
      float psum = (ps[0] + ps[1]) + (ps[2] + ps[3]);
      psum += __shfl_xor(psum, 16);
      psum += __shfl_xor(psum, 32);
      l_i += psum;
    } else {
      // diagonal block: full per-element causal+selection masking
      float sc[4][4];
      float rmax = -1e30f;
#pragma unroll
      for (int nt = 0; nt < 4; ++nt)
#pragma unroll
        for (int i = 0; i < 4; ++i) {
          int key = Lq * 16 + nt * 4 + i;   // actual key (permuted kf order)
          bool ok = (msel != 0.f) && (key <= m0 + Lm);
          float v = ok ? S[nt][i] : -1e30f;
          sc[nt][i] = v;
          rmax = fmaxf(rmax, v);
        }
      rmax = fmaxf(rmax, __shfl_xor(rmax, 16));
      rmax = fmaxf(rmax, __shfl_xor(rmax, 32));
      float mn = fmaxf(m_i, rmax);
      float av = __builtin_amdgcn_exp2f(m_i - mn);
      m_i = mn;
      float ps[4];
#pragma unroll
      for (int nt = 0; nt < 4; ++nt) {
        float s0 = 0.f;
#pragma unroll
        for (int i = 0; i < 4; ++i) {
          float a = __builtin_amdgcn_exp2f(sc[nt][i] - mn);
          p[nt][i] = a;
          s0 += a;
        }
        ps[nt] = s0;
      }
      float psum = (ps[0] + ps[1]) + (ps[2] + ps[3]);
      psum += __shfl_xor(psum, 16);
      psum += __shfl_xor(psum, 32);
      l_i = l_i * av + psum;
#pragma unroll
      for (int n0 = 0; n0 < 8; ++n0) Oacc[n0] *= av;
    }

    // P row is lane-contiguous: pack to f16 pairs, 2x b128 store, 2x b128 read.
    asm volatile("s_waitcnt lgkmcnt(0)" ::: "memory");  // WAR vs last iter's P reads
    u32x4 w0, w1;
    {
      auto c00 = __builtin_amdgcn_cvt_pkrtz(p[0][0], p[0][1]);
      auto c01 = __builtin_amdgcn_cvt_pkrtz(p[0][2], p[0][3]);
      auto c10 = __builtin_amdgcn_cvt_pkrtz(p[1][0], p[1][1]);
      auto c11 = __builtin_amdgcn_cvt_pkrtz(p[1][2], p[1][3]);
      auto c20 = __builtin_amdgcn_cvt_pkrtz(p[2][0], p[2][1]);
      auto c21 = __builtin_amdgcn_cvt_pkrtz(p[2][2], p[2][3]);
      auto c30 = __builtin_amdgcn_cvt_pkrtz(p[3][0], p[3][1]);
      auto c31 = __builtin_amdgcn_cvt_pkrtz(p[3][2], p[3][3]);
      w0[0] = __builtin_bit_cast(unsigned, c00); w0[1] = __builtin_bit_cast(unsigned, c01);
      w0[2] = __builtin_bit_cast(unsigned, c10); w0[3] = __builtin_bit_cast(unsigned, c11);
      w1[0] = __builtin_bit_cast(unsigned, c20); w1[1] = __builtin_bit_cast(unsigned, c21);
      w1[2] = __builtin_bit_cast(unsigned, c30); w1[3] = __builtin_bit_cast(unsigned, c31);
    }
    *(u32x4*)(pw + Lm * 72 + Lq * 16) = w0;
    *(u32x4*)(pw + Lm * 72 + Lq * 16 + 8) = w1;
    asm volatile("s_waitcnt lgkmcnt(0)" ::: "memory");  // RAW: writes visible

    // PV: V from registers (compiler waits vmcnt for vr exactly here)
#pragma unroll
    for (int kc = 0; kc < 2; ++kc) {
      half8 pfr = *(const half8*)(pw + Lm * 72 + kc * 32 + Lq * 8);  // B: P^T k-slots
#pragma unroll
      for (int n0 = 0; n0 < 8; ++n0)
        Oacc[n0] = __builtin_amdgcn_mfma_f32_16x16x32_f16(vr[n0 * 2 + kc], pfr, Oacc[n0], 0, 0, 0);
    }

    if (nxt < 0) break;
    loadV(nxt);                        // 16 dwordx4, stay in flight across barrier
    // counted: only the 6 K stages (oldest) must land; 16 V loads cross.
    asm volatile("s_waitcnt vmcnt(16)\n\ts_barrier" ::: "memory");
    cur ^= 1;
    kb = nxt;
  }

  float inv = 1.f / l_i;
  float* orow = out + (long)(t0 + m0 + Lm) * 2048 + h * 128 + Lq * 4;
#pragma unroll
  for (int n0 = 0; n0 < 8; ++n0) {
    f32x4 o = Oacc[n0] * inv;
    *(f32x4*)(orow + n0 * 16) = o;
  }
}

extern "C" void kernel_launch(void* const* d_in, const int* in_sizes, int n_in,
                              void* d_out, int out_size, void* d_ws, size_t ws_size,
                              hipStream_t stream) {
  const float* q = (const float*)d_in[0];
  const float* k = (const float*)d_in[1];
  const float* v = (const float*)d_in[2];
  const int* idx = (const int*)d_in[3];
  _Float16* kf = (_Float16*)d_ws;                       // 2048 blk * 12288 f16 = 50.3 MB
  _Float16* vf = kf + (size_t)2048 * 12288;             // 2048 blk * 8192  f16 = 33.6 MB
  float* out = (float*)d_out;
  kv_prep<<<2048, 256, 0, stream>>>(k, v, kf, vf);
  attn_main<<<2048, 256, 0, stream>>>(q, idx, kf, vf, out);
}

// Round 3
// 414.920 us; speedup vs baseline: 1.0597x; 1.0597x over previous
//
#include <hip/hip_runtime.h>

// SelectiveAttnMLA on MI355X (gfx950).
// B=4 S=2048 Hq=16 G=4 D=192 DV=128 BLK=64 NB=32 TOPK=16, out fp32 (8192x2048).
//
// R6: occupancy-first pipeline. LDS = 24KB K + 16KB V = 40960B exactly ->
//     4 blocks/CU (was 2). Pbuf LDS round-trip replaced by 16x ds_bpermute
//     P-exchange; block-union mask computed via per-lane row reads + wave OR
//     (no LDS, no prologue syncthreads). Single-buffered K and V with
//     3-barrier schedule that hides all staging latency:
//       top:  vmcnt(4)+bar   (K landed; V's 4 loads still in flight)
//       QK^T
//       mid:  vmcnt(0)+lgkm(0)+bar (V landed ~free; K reads retired) -> stageK(nxt)
//       softmax + P-exchange + PV
//       bot:  lgkm(0)+bar    (V reads retired) -> stageV(nxt)

typedef __attribute__((ext_vector_type(8))) _Float16 half8;
typedef __attribute__((ext_vector_type(4))) float f32x4;
typedef __attribute__((ext_vector_type(4))) unsigned int u32x4;

__device__ __forceinline__ half8 cvt8(const float4* p) {
  float4 a = p[0], b = p[1];
  half8 r;
  r[0] = (_Float16)a.x; r[1] = (_Float16)a.y; r[2] = (_Float16)a.z; r[3] = (_Float16)a.w;
  r[4] = (_Float16)b.x; r[5] = (_Float16)b.y; r[6] = (_Float16)b.z; r[7] = (_Float16)b.w;
  return r;
}

__device__ __forceinline__ half8 cvt8s(const float4* p, float s) {
  float4 a = p[0], b = p[1];
  half8 r;
  r[0] = (_Float16)(a.x * s); r[1] = (_Float16)(a.y * s);
  r[2] = (_Float16)(a.z * s); r[3] = (_Float16)(a.w * s);
  r[4] = (_Float16)(b.x * s); r[5] = (_Float16)(b.y * s);
  r[6] = (_Float16)(b.z * s); r[7] = (_Float16)(b.w * s);
  return r;
}

__device__ __forceinline__ void async16(const void* g, void* l) {
  __builtin_amdgcn_global_load_lds(
      (const __attribute__((address_space(1))) void*)g,
      (__attribute__((address_space(3))) void*)l, 16, 0, 0);
}

__device__ __forceinline__ f32x4 vmax4(f32x4 a, f32x4 b) {
  f32x4 r;
  r[0] = fmaxf(a[0], b[0]); r[1] = fmaxf(a[1], b[1]);
  r[2] = fmaxf(a[2], b[2]); r[3] = fmaxf(a[3], b[3]);
  return r;
}

// ---------------- fused K/V fragment prepass (unchanged) ----------------
__global__ __launch_bounds__(256) void kv_prep(const float* __restrict__ k,
                                               const float* __restrict__ v,
                                               _Float16* __restrict__ kf,
                                               _Float16* __restrict__ vf) {
  __shared__ float lb[64 * 196];      // K phase: [64][196]; V phase: [64][132]
  int blk = blockIdx.x;               // (b*16+h)*32 + kb
  int bh = blk >> 5, kb = blk & 31;
  int b = bh >> 4, h = bh & 15;
  int tid = threadIdx.x;

  // ---- K: load 64 rows x 192 f32, coalesced ----
  const float* ksrc = k + ((long)(b * 2048 + kb * 64) * 16 + h) * 192;
#pragma unroll
  for (int it = 0; it < 12; ++it) {
    int idx = it * 256 + tid;         // 3072 float4
    int kk = idx / 48, c4 = idx - kk * 48;
    *(float4*)(&lb[kk * 196 + c4 * 4]) = *(const float4*)(ksrc + (long)kk * 3072 + c4 * 4);
  }
  __syncthreads();
  _Float16* kdst = kf + (long)blk * 12288;
#pragma unroll
  for (int it = 0; it < 6; ++it) {
    int oct = it * 256 + tid;         // 1536 octets
    int frag = oct >> 6, lane = oct & 63;
    int ntile = frag / 6, kc = frag - ntile * 6;
    int lm = lane & 15;
    // permuted row: stored slot (ntile, lm) <- actual key (lm>>2)*16 + ntile*4 + (lm&3)
    int n = ((lm >> 2) << 4) + ntile * 4 + (lm & 3);
    int d = kc * 32 + ((lane >> 4) << 3);
    *(half8*)(kdst + (long)oct * 8) = cvt8((const float4*)(&lb[n * 196 + d]));
  }
  __syncthreads();

  // ---- V: load 64 rows x 128 f32, coalesced; emit transposed frags ----
  const float* vsrc = v + ((long)(b * 2048 + kb * 64) * 16 + h) * 128;
#pragma unroll
  for (int it = 0; it < 8; ++it) {
    int idx = it * 256 + tid;         // 2048 float4
    int kk = idx >> 5, c4 = idx & 31;
    *(float4*)(&lb[kk * 132 + c4 * 4]) = *(const float4*)(vsrc + (long)kk * 2048 + c4 * 4);
  }
  __syncthreads();
  _Float16* vdst = vf + (long)blk * 8192;
#pragma unroll
  for (int it = 0; it < 4; ++it) {
    int oct = it * 256 + tid;         // 1024 octets
    int frag = oct >> 6, lane = oct & 63;
    int n0 = frag >> 1, kc = frag & 1;
    int dv = n0 * 16 + (lane & 15);
    int kbase = kc * 32 + ((lane >> 4) << 3);
    half8 o;
#pragma unroll
    for (int j = 0; j < 8; ++j) o[j] = (_Float16)lb[(kbase + j) * 132 + dv];
    *(half8*)(vdst + (long)oct * 8) = o;
  }
}

// ---------------- main attention (swapped operands, 40KB LDS, 4 blk/CU) ----------------
__global__ __launch_bounds__(256, 4) void attn_main(const float* __restrict__ q,
                                                    const int* __restrict__ idx,
                                                    const _Float16* __restrict__ kf,
                                                    const _Float16* __restrict__ vf,
                                                    float* __restrict__ out) {
  constexpr float SCL = 0.07216878364870322f * 1.4426950408889634f;  // sm_scale*log2e
  int id = (int)blockIdx.x;
  int qb = 31 - (id >> 6);            // qb swizzle: CU gets mixed qb, fixed (b,h)
  int h = id & 15, b = (id >> 4) & 3, g = h >> 2;
  int tid = threadIdx.x;
  int w = tid >> 6, L = tid & 63;
  int Lm = L & 15, Lq = L >> 4;
  int m0 = w * 16;
  int t0 = b * 2048 + qb * 64;

  __shared__ __align__(16) char sh_k[24576];   // K frags, single buffer
  __shared__ __align__(16) char sh_v[16384];   // V frags, single buffer (40960B total)

  const char* kfb = (const char*)(kf + (long)((b * 16 + h) * 32) * 12288);
  const char* vfb = (const char*)(vf + (long)((b * 16 + h) * 32) * 8192);

  auto stageK = [&](int kb) {
#pragma unroll
    for (int c = 0; c < 6; ++c) {
      int ch = w + c * 4;
      async16(kfb + (long)kb * 24576 + ch * 1024 + L * 16, sh_k + ch * 1024);
    }
  };
  auto stageV = [&](int kb) {
#pragma unroll
    for (int c = 0; c < 4; ++c) {
      int ch = w + c * 4;
      async16(vfb + (long)kb * 16384 + ch * 1024 + L * 16, sh_v + ch * 1024);
    }
  };

  // Q as B-operand: col = Lm (query row), k-slots = d
  half8 qa[6];
  const float* qrow = q + ((long)(t0 + m0 + Lm) * 16 + h) * 192;
#pragma unroll
  for (int c = 0; c < 6; ++c) qa[c] = cvt8s((const float4*)(qrow + c * 32 + Lq * 8), SCL);

  // selection masks without LDS: lane L reads the 16 picks of block-row L.
  unsigned rm = 0;
  {
    const int4* ip = (const int4*)(idx + ((long)(t0 + L) * 4 + g) * 16);
#pragma unroll
    for (int u = 0; u < 4; ++u) {
      int4 iv = ip[u];
      rm |= (1u << iv.x) | (1u << iv.y) | (1u << iv.z) | (1u << iv.w);
    }
  }
  unsigned bm = rm;
#pragma unroll
  for (int o = 1; o < 64; o <<= 1) bm |= __shfl_xor(bm, o, 64);   // block union
  unsigned mrow = __shfl(rm, m0 + Lm, 64);    // this lane's query row mask
  unsigned bmask = bm & ((2u << qb) - 1);     // bits 0..qb (qb=31 wraps to all-ones)

  stageK(0); stageV(0);                        // block 0 always selected

  f32x4 Oacc[8];                      // O^T tiles: row = dv (Lq*4+i), col = q (Lm)
#pragma unroll
  for (int n0 = 0; n0 < 8; ++n0) Oacc[n0] = (f32x4){0.f, 0.f, 0.f, 0.f};
  float m_i = -1e30f, l_i = 0.f;

  unsigned rem = bmask;               // bit 0 always set
  int kb = 0;

  for (;;) {
    rem &= rem - 1;
    int nxt = rem ? (int)__builtin_ctz(rem) : -1;

    // K(kb) landed everywhere (each wave waits its own 6 K; V's 4 loads fly on)
    asm volatile("s_waitcnt vmcnt(4)\n\ts_barrier" ::: "memory");

    const half8* lkf = (const half8*)sh_k;
    // S^T = K Q^T: lane holds scores of query Lm for actual keys Lq*16 + nt*4 + i
    f32x4 S[4];
#pragma unroll
    for (int nt = 0; nt < 4; ++nt) {
      f32x4 acc = {0.f, 0.f, 0.f, 0.f};
#pragma unroll
      for (int c = 0; c < 6; ++c)
        acc = __builtin_amdgcn_mfma_f32_16x16x32_f16(lkf[(nt * 6 + c) * 64 + L], qa[c], acc, 0, 0, 0);
      S[nt] = acc;
    }

    // V(kb) visible to all (~free: flew during QK^T); K reads retired -> safe
    // to overwrite sh_k with next block while softmax+PV run.
    asm volatile("s_waitcnt vmcnt(0) lgkmcnt(0)\n\ts_barrier" ::: "memory");
    if (nxt >= 0) stageK(nxt);

    float p[4][4];
    float msel = ((mrow >> kb) & 1u) ? 1.0f : 0.0f;
    if (kb != qb) {
      // selection via per-row 0/1 multiply; inflated row-max from unselected
      // rows is exact (softmax shift-invariance), p*0 kills the values.
      f32x4 t = vmax4(vmax4(S[0], S[1]), vmax4(S[2], S[3]));
      float rmax = fmaxf(fmaxf(t[0], t[1]), fmaxf(t[2], t[3]));
      rmax = fmaxf(rmax, __shfl_xor(rmax, 16));
      rmax = fmaxf(rmax, __shfl_xor(rmax, 32));
      if (__any(rmax > m_i)) {
        float mn = fmaxf(m_i, rmax);
        float av = __builtin_amdgcn_exp2f(m_i - mn);
        m_i = mn;
        l_i *= av;
#pragma unroll
        for (int n0 = 0; n0 < 8; ++n0) Oacc[n0] *= av;
      }
      float ps[4];
#pragma unroll
      for (int nt = 0; nt < 4; ++nt) {
        float s0 = 0.f, s1 = 0.f;
#pragma unroll
        for (int i = 0; i < 4; i += 2) {
          float a = __builtin_amdgcn_exp2f(S[nt][i] - m_i) * msel;
          float c = __builtin_amdgcn_exp2f(S[nt][i + 1] - m_i) * msel;
          p[nt][i] = a; p[nt][i + 1] = c;
          s0 += a; s1 += c;
        }
        ps[nt] = s0 + s1;
      }
      float psum = (ps[0] + ps[1]) + (ps[2] + ps[3]);
      psum += __shfl_xor(psum, 16);
      psum += __shfl_xor(psum, 32);
      l_i += psum;
    } else {
      // diagonal block: full per-element causal+selection masking
      float sc[4][4];
      float rmax = -1e30f;
#pragma unroll
      for (int nt = 0; nt < 4; ++nt)
#pragma unroll
        for (int i = 0; i < 4; ++i) {
          int key = Lq * 16 + nt * 4 + i;   // actual key (permuted kf order)
          bool ok = (msel != 0.f) && (key <= m0 + Lm);
          float v = ok ? S[nt][i] : -1e30f;
          sc[nt][i] = v;
          rmax = fmaxf(rmax, v);
        }
      rmax = fmaxf(rmax, __shfl_xor(rmax, 16));
      rmax = fmaxf(rmax, __shfl_xor(rmax, 32));
      float mn = fmaxf(m_i, rmax);
      float av = __builtin_amdgcn_exp2f(m_i - mn);
      m_i = mn;
      float ps[4];
#pragma unroll
      for (int nt = 0; nt < 4; ++nt) {
        float s0 = 0.f;
#pragma unroll
        for (int i = 0; i < 4; ++i) {
          float a = __builtin_amdgcn_exp2f(sc[nt][i] - mn);
          p[nt][i] = a;
          s0 += a;
        }
        ps[nt] = s0;
      }
      float psum = (ps[0] + ps[1]) + (ps[2] + ps[3]);
      psum += __shfl_xor(psum, 16);
      psum += __shfl_xor(psum, 32);
      l_i = l_i * av + psum;
#pragma unroll
      for (int n0 = 0; n0 < 8; ++n0) Oacc[n0] *= av;
    }

    // pack P to f16 pairs: word t covers keys Lq*16 + 2t
    unsigned w8[8];
#pragma unroll
    for (int nt = 0; nt < 4; ++nt) {
      w8[2 * nt]     = __builtin_bit_cast(unsigned, __builtin_amdgcn_cvt_pkrtz(p[nt][0], p[nt][1]));
      w8[2 * nt + 1] = __builtin_bit_cast(unsigned, __builtin_amdgcn_cvt_pkrtz(p[nt][2], p[nt][3]));
    }
    // cross-lane exchange: dest (Lm,Lq),kc needs keys kc*32+Lq*8+2u from
    // src lane ((Lq>>1)+2kc)*16+Lm, src word (Lq&1)*4+u.
    half8 pfr[2];
#pragma unroll
    for (int kc = 0; kc < 2; ++kc) {
      int src = ((Lq >> 1) + 2 * kc) * 16 + Lm;
      u32x4 d;
#pragma unroll
      for (int u = 0; u < 4; ++u) {
        unsigned lo = (unsigned)__shfl((int)w8[u], src, 64);
        unsigned hi = (unsigned)__shfl((int)w8[u + 4], src, 64);
        d[u] = (Lq & 1) ? hi : lo;
      }
      pfr[kc] = __builtin_bit_cast(half8, d);
    }

    // PV: O^T += V^T P^T, V from LDS
    const half8* lvf = (const half8*)sh_v;
#pragma unroll
    for (int kc = 0; kc < 2; ++kc)
#pragma unroll
      for (int n0 = 0; n0 < 8; ++n0)
        Oacc[n0] = __builtin_amdgcn_mfma_f32_16x16x32_f16(lvf[(n0 * 2 + kc) * 64 + L], pfr[kc], Oacc[n0], 0, 0, 0);

    if (nxt < 0) break;
    // V reads retired -> safe to overwrite sh_v; its latency hides under next QK^T
    asm volatile("s_waitcnt lgkmcnt(0)\n\ts_barrier" ::: "memory");
    stageV(nxt);
    kb = nxt;
  }

  float inv = 1.f / l_i;
  float* orow = out + (long)(t0 + m0 + Lm) * 2048 + h * 128 + Lq * 4;
#pragma unroll
  for (int n0 = 0; n0 < 8; ++n0) {
    f32x4 o = Oacc[n0] * inv;
    *(f32x4*)(orow + n0 * 16) = o;
  }
}

extern "C" void kernel_launch(void* const* d_in, const int* in_sizes, int n_in,
                              void* d_out, int out_size, void* d_ws, size_t ws_size,
                              hipStream_t stream) {
  const float* q = (const float*)d_in[0];
  const float* k = (const float*)d_in[1];
  const float* v = (const float*)d_in[2];
  const int* idx = (const int*)d_in[3];
  _Float16* kf = (_Float16*)d_ws;                       // 2048 blk * 12288 f16 = 50.3 MB
  _Float16* vf = kf + (size_t)2048 * 12288;             // 2048 blk * 8192  f16 = 33.6 MB
  float* out = (float*)d_out;
  kv_prep<<<2048, 256, 0, stream>>>(k, v, kf, vf);
  attn_main<<<2048, 256, 0, stream>>>(q, idx, kf, vf, out);
}